// Round 14
// baseline (1044.400 us; speedup 1.0000x reference)
//
#include <hip/hip_runtime.h>
#include <cstdint>

typedef _Float16 f16;
typedef __attribute__((ext_vector_type(8))) _Float16 v8h;
typedef __attribute__((ext_vector_type(4))) float v4f;

#define LO_SCALE 4096.0f           // 2^12
#define LO_INV   2.44140625e-4f    // 2^-12

// fp32 -> (hi, lo*2^12) fp16 pair. hi + lo*2^-12 represents f to ~2^-23 rel.
__device__ __forceinline__ void split2(float f, f16& h, f16& l) {
    h = (f16)f;
    l = (f16)((f - (float)h) * LO_SCALE);
}

// global -> LDS async copy, 16B per lane (wave-uniform LDS base + lane*16).
__device__ __forceinline__ void gload_lds16(const void* g, void* l) {
    __builtin_amdgcn_global_load_lds(
        (const __attribute__((address_space(1))) unsigned int*)(uintptr_t)g,
        (__attribute__((address_space(3))) unsigned int*)(unsigned int)(uintptr_t)l,
        16, 0, 0);
}

// ---------------------------------------------------------------------------
// 2-limb fp16 NT GEMM (128^2, 2-barrier). Kept ONLY for the tiny Vt GEMM.
// ---------------------------------------------------------------------------
__global__ __launch_bounds__(256)
void gemm_nt_2limb(const f16* __restrict__ A1, const f16* __restrict__ A2,
                   const f16* __restrict__ B1, const f16* __restrict__ B2,
                   float* __restrict__ C32, f16* __restrict__ Ch,
                   f16* __restrict__ Cl, int mode, int N, int K)
{
    __shared__ f16 lds[4 * 128 * 32];   // 32 KB: A1,A2,B1,B2 tiles
    f16* lA1 = lds;
    f16* lA2 = lds + 128 * 32;
    f16* lB1 = lds + 2 * 128 * 32;
    f16* lB2 = lds + 3 * 128 * 32;

    const int tid  = threadIdx.x;
    const int lane = tid & 63;
    const int wave = tid >> 6;
    const int wm = wave >> 1, wn = wave & 1;
    const int fr = lane & 15, quad = lane >> 4;
    const int row0 = blockIdx.y * 128;
    const int col0 = blockIdx.x * 128;
    const int l4 = lane >> 2;
    const int c8 = (lane & 3) * 8;

    v4f accB[4][4], accS[4][4];
#pragma unroll
    for (int i = 0; i < 4; ++i)
#pragma unroll
        for (int j = 0; j < 4; ++j) {
            accB[i][j] = {0.f, 0.f, 0.f, 0.f};
            accS[i][j] = {0.f, 0.f, 0.f, 0.f};
        }

    for (int k0 = 0; k0 < K; k0 += 32) {
#pragma unroll
        for (int t = 0; t < 2; ++t) {
            const int slot = wave + 4 * t;
            const int r = slot * 16 + l4;
            const size_t ga = (size_t)(row0 + r) * K + (k0 + c8);
            const size_t gb = (size_t)(col0 + r) * K + (k0 + c8);
            const unsigned loff = slot * 1024;
            gload_lds16(A1 + ga, (char*)lA1 + loff);
            gload_lds16(A2 + ga, (char*)lA2 + loff);
            gload_lds16(B1 + gb, (char*)lB1 + loff);
            gload_lds16(B2 + gb, (char*)lB2 + loff);
        }
        __syncthreads();

        v8h a1[4], a2[4], b1[4], b2[4];
#pragma unroll
        for (int i = 0; i < 4; ++i) {
            const int off = (wm * 64 + i * 16 + fr) * 32 + quad * 8;
            a1[i] = *(const v8h*)&lA1[off];
            a2[i] = *(const v8h*)&lA2[off];
        }
#pragma unroll
        for (int j = 0; j < 4; ++j) {
            const int off = (wn * 64 + j * 16 + fr) * 32 + quad * 8;
            b1[j] = *(const v8h*)&lB1[off];
            b2[j] = *(const v8h*)&lB2[off];
        }
#pragma unroll
        for (int i = 0; i < 4; ++i)
#pragma unroll
            for (int j = 0; j < 4; ++j) {
                accB[i][j] = __builtin_amdgcn_mfma_f32_16x16x32_f16(a1[i], b1[j], accB[i][j], 0, 0, 0);
                accS[i][j] = __builtin_amdgcn_mfma_f32_16x16x32_f16(a2[i], b1[j], accS[i][j], 0, 0, 0);
                accS[i][j] = __builtin_amdgcn_mfma_f32_16x16x32_f16(a1[i], b2[j], accS[i][j], 0, 0, 0);
            }
        __syncthreads();
    }

    // C/D layout (verified): row = quad*4 + reg, col = lane&15
#pragma unroll
    for (int i = 0; i < 4; ++i)
#pragma unroll
        for (int j = 0; j < 4; ++j) {
            const int row = row0 + wm * 64 + i * 16 + quad * 4;
            const int col = col0 + wn * 64 + j * 16 + fr;
#pragma unroll
            for (int r = 0; r < 4; ++r) {
                const float v = accB[i][j][r] + accS[i][j][r] * LO_INV;
                const size_t off = (size_t)(row + r) * N + col;
                if (mode == 0) {
                    C32[off] = v;
                } else if (mode == 1) {
                    f16 h, l; split2(v, h, l);
                    Ch[off] = h; Cl[off] = l;
                } else {
                    C32[off] = v;
                    Ch[off] = (f16)v;
                }
            }
        }
}

// ---------------------------------------------------------------------------
// 2-limb fp16 NT GEMM, 256x128 tile, BK=32, 8 waves, phase-split schedule
// + T2 swizzle + XCD-chunked mapping. K~ only (writes C32 fp32 + Ch f16).
// Verified R7.
// ---------------------------------------------------------------------------
__global__ __launch_bounds__(512)
void gemm_nt_2limb_256(const f16* __restrict__ A1, const f16* __restrict__ A2,
                       const f16* __restrict__ B1, const f16* __restrict__ B2,
                       float* __restrict__ C32, f16* __restrict__ Ch,
                       int N, int K)
{
    // [buf(2)][A1 16K | A2 16K | B1 8K | B2 8K] = 96 KB
    __shared__ f16 lds[2 * 24576];

    const int bid = blockIdx.x;
    const int lid = (bid & 7) * 32 + (bid >> 3);   // XCD-chunked, bijective
    const int col0 = (lid & 7) * 128;              // N strip (8)
    const int row0 = (lid >> 3) * 256;             // M strip (32)

    const int tid  = threadIdx.x;
    const int lane = tid & 63;
    const int wave = tid >> 6;          // 0..7
    const int wm = wave >> 1;           // 0..3  (64-row strip)
    const int wn = wave & 1;            // 0..1  (64-col strip)
    const int fr = lane & 15, quad = lane >> 4;
    const int NT = K >> 5;

    const int trow = tid >> 2;          // 0..127
    const int tchunk = tid & 3;

    auto STAGE = [&](int T) {
        const unsigned bufB = (unsigned)(T & 1) * 49152u;   // bytes
        const int k0 = T * 32;
#pragma unroll
        for (int rd = 0; rd < 2; ++rd) {
            const int r = trow + rd * 128;
            const int sc = (tchunk ^ ((r >> 1) & 3)) * 8;   // f16 units
            const size_t ga = (size_t)(row0 + r) * K + k0 + sc;
            const unsigned dof = (unsigned)(rd * 8192 + wave * 1024);
            gload_lds16(A1 + ga, (char*)lds + bufB + dof);
            gload_lds16(A2 + ga, (char*)lds + bufB + 16384u + dof);
        }
        {
            const int r = trow;
            const int sc = (tchunk ^ ((r >> 1) & 3)) * 8;
            const size_t gb = (size_t)(col0 + r) * K + k0 + sc;
            const unsigned dof = (unsigned)(wave * 1024);
            gload_lds16(B1 + gb, (char*)lds + bufB + 32768u + dof);
            gload_lds16(B2 + gb, (char*)lds + bufB + 40960u + dof);
        }
    };

    auto LRD = [&](const f16* base, int row) {
        return *(const v8h*)&base[row * 32 + ((quad ^ ((row >> 1) & 3)) * 8)];
    };

    v4f accB[4][4], accS[4][4];
#pragma unroll
    for (int i = 0; i < 4; ++i)
#pragma unroll
        for (int j = 0; j < 4; ++j) {
            accB[i][j] = {0.f, 0.f, 0.f, 0.f};
            accS[i][j] = {0.f, 0.f, 0.f, 0.f};
        }

    STAGE(0);
    asm volatile("s_waitcnt vmcnt(0)" ::: "memory");
    __builtin_amdgcn_s_barrier();

    for (int t = 0; t < NT; ++t) {
        const int bc = (t & 1) * 24576;             // f16 units
        const f16* lA1 = lds + bc;
        const f16* lA2 = lds + bc + 8192;
        const f16* lB1 = lds + bc + 16384;
        const f16* lB2 = lds + bc + 20480;

        // ---- phase 0: all B frags + A i=0; issue next tile ----
        v8h b1[4], b2[4];
#pragma unroll
        for (int j = 0; j < 4; ++j) {
            b1[j] = LRD(lB1, wn * 64 + j * 16 + fr);
            b2[j] = LRD(lB2, wn * 64 + j * 16 + fr);
        }
        {
            v8h a1 = LRD(lA1, wm * 64 + 0 + fr);
            v8h a2 = LRD(lA2, wm * 64 + 0 + fr);
            if (t + 1 < NT) STAGE(t + 1);
            __builtin_amdgcn_s_barrier();
            asm volatile("s_waitcnt lgkmcnt(0)" ::: "memory");
            __builtin_amdgcn_s_setprio(1);
#pragma unroll
            for (int j = 0; j < 4; ++j) {
                accB[0][j] = __builtin_amdgcn_mfma_f32_16x16x32_f16(a1, b1[j], accB[0][j], 0, 0, 0);
                accS[0][j] = __builtin_amdgcn_mfma_f32_16x16x32_f16(a2, b1[j], accS[0][j], 0, 0, 0);
                accS[0][j] = __builtin_amdgcn_mfma_f32_16x16x32_f16(a1, b2[j], accS[0][j], 0, 0, 0);
            }
            __builtin_amdgcn_s_setprio(0);
            __builtin_amdgcn_s_barrier();
        }

        // ---- phases 1..3: A i=p; phase 3 carries the tile vmcnt ----
#pragma unroll
        for (int p = 1; p < 4; ++p) {
            v8h a1 = LRD(lA1, wm * 64 + p * 16 + fr);
            v8h a2 = LRD(lA2, wm * 64 + p * 16 + fr);
            __builtin_amdgcn_s_barrier();
            asm volatile("s_waitcnt lgkmcnt(0)" ::: "memory");
            __builtin_amdgcn_s_setprio(1);
#pragma unroll
            for (int j = 0; j < 4; ++j) {
                accB[p][j] = __builtin_amdgcn_mfma_f32_16x16x32_f16(a1, b1[j], accB[p][j], 0, 0, 0);
                accS[p][j] = __builtin_amdgcn_mfma_f32_16x16x32_f16(a2, b1[j], accS[p][j], 0, 0, 0);
                accS[p][j] = __builtin_amdgcn_mfma_f32_16x16x32_f16(a1, b2[j], accS[p][j], 0, 0, 0);
            }
            __builtin_amdgcn_s_setprio(0);
            if (p == 3)
                asm volatile("s_waitcnt vmcnt(0)" ::: "memory");
            __builtin_amdgcn_s_barrier();
        }
    }

    // C/D layout (verified): row = quad*4 + reg, col = lane&15; C32 + Ch
#pragma unroll
    for (int i = 0; i < 4; ++i)
#pragma unroll
        for (int j = 0; j < 4; ++j) {
            const int row = row0 + wm * 64 + i * 16 + quad * 4;
            const int col = col0 + wn * 64 + j * 16 + fr;
#pragma unroll
            for (int r = 0; r < 4; ++r) {
                const float v = accB[i][j][r] + accS[i][j][r] * LO_INV;
                const size_t off = (size_t)(row + r) * N + col;
                C32[off] = v;
                Ch[off] = (f16)v;
            }
        }
}

// ---------------------------------------------------------------------------
// Single-limb f16 NT GEMM, 256x256 tile, BK=64, 8 waves, phase-split +
// T2 XOR-swizzle (verified R6). Batched via blockIdx.z.
// ---------------------------------------------------------------------------
__global__ __launch_bounds__(512)
void gemm_nt_f16_256(const f16* __restrict__ A, const f16* __restrict__ B,
                     f16* __restrict__ C, int N, int K,
                     size_t sA, size_t sB, size_t sC)
{
    // [buf(2)][op(2): A,B][256 rows][64 k] f16 = 128 KB
    __shared__ f16 lds[2 * 2 * 256 * 64];

    const int bz = blockIdx.z;
    A += (size_t)bz * sA; B += (size_t)bz * sB; C += (size_t)bz * sC;

    const int tid  = threadIdx.x;
    const int lane = tid & 63;
    const int wave = tid >> 6;          // 0..7
    const int wm = wave >> 2;           // 0..1  (M half)
    const int wn = wave & 3;            // 0..3  (N quarter)
    const int fr = lane & 15, quad = lane >> 4;
    const int row0 = blockIdx.y * 256;
    const int col0 = blockIdx.x * 256;
    const int NT = K >> 6;

    const int rsub = tid >> 3;          // 0..63: row within a 64-row group
    const int csub = (((tid & 7) ^ ((tid >> 3) & 7)) * 8);

    auto STAGE = [&](int T) {
        const unsigned bufB = (unsigned)(T & 1) * 65536u;   // bytes
#pragma unroll
        for (int q = 0; q < 4; ++q) {
            const f16* op = (q >= 2) ? B : A;
            const int r0 = ((q >= 2) ? col0 : row0) + (q & 1) * 128;
#pragma unroll
            for (int t2 = 0; t2 < 2; ++t2) {
                const f16* g = op + (size_t)(r0 + t2 * 64 + rsub) * K + T * 64 + csub;
                gload_lds16(g, (char*)lds + bufB + (unsigned)(q >> 1) * 32768u
                                 + (unsigned)(q & 1) * 16384u
                                 + (unsigned)(t2 * 8192 + wave * 1024));
            }
        }
    };

    auto LRD = [&](const f16* base, int row, int ks) {
        return *(const v8h*)&base[row * 64 + (((ks * 4 + quad) ^ (row & 7)) * 8)];
    };

    v4f acc[8][4];
#pragma unroll
    for (int i = 0; i < 8; ++i)
#pragma unroll
        for (int j = 0; j < 4; ++j)
            acc[i][j] = {0.f, 0.f, 0.f, 0.f};

    STAGE(0);
    asm volatile("s_waitcnt vmcnt(0)" ::: "memory");
    __builtin_amdgcn_s_barrier();

    for (int t = 0; t < NT; ++t) {
        const int bc = (t & 1) * 32768;             // f16 units
        const f16* lA = lds + bc;
        const f16* lB = lds + bc + 16384;

        // ---- phase 0: B-frags (whole tile) + A i=0,1; issue next tile ----
        v8h bfr[4][2];
#pragma unroll
        for (int j = 0; j < 4; ++j)
#pragma unroll
            for (int ks = 0; ks < 2; ++ks)
                bfr[j][ks] = LRD(lB, wn * 64 + j * 16 + fr, ks);
        {
            v8h a0[2], a1[2];
#pragma unroll
            for (int ks = 0; ks < 2; ++ks) {
                a0[ks] = LRD(lA, wm * 128 + 0 + fr, ks);
                a1[ks] = LRD(lA, wm * 128 + 16 + fr, ks);
            }
            if (t + 1 < NT) STAGE(t + 1);
            __builtin_amdgcn_s_barrier();
            asm volatile("s_waitcnt lgkmcnt(0)" ::: "memory");
            __builtin_amdgcn_s_setprio(1);
#pragma unroll
            for (int j = 0; j < 4; ++j) {
                acc[0][j] = __builtin_amdgcn_mfma_f32_16x16x32_f16(a0[0], bfr[j][0], acc[0][j], 0, 0, 0);
                acc[0][j] = __builtin_amdgcn_mfma_f32_16x16x32_f16(a0[1], bfr[j][1], acc[0][j], 0, 0, 0);
                acc[1][j] = __builtin_amdgcn_mfma_f32_16x16x32_f16(a1[0], bfr[j][0], acc[1][j], 0, 0, 0);
                acc[1][j] = __builtin_amdgcn_mfma_f32_16x16x32_f16(a1[1], bfr[j][1], acc[1][j], 0, 0, 0);
            }
            __builtin_amdgcn_s_setprio(0);
            __builtin_amdgcn_s_barrier();
        }

        // ---- phases 1..3: A i=2p..2p+1; phase 3 carries the tile vmcnt ----
#pragma unroll
        for (int p = 1; p < 4; ++p) {
            v8h ap[2][2];
#pragma unroll
            for (int u = 0; u < 2; ++u)
#pragma unroll
                for (int ks = 0; ks < 2; ++ks)
                    ap[u][ks] = LRD(lA, wm * 128 + (p * 2 + u) * 16 + fr, ks);
            __builtin_amdgcn_s_barrier();
            asm volatile("s_waitcnt lgkmcnt(0)" ::: "memory");
            __builtin_amdgcn_s_setprio(1);
#pragma unroll
            for (int u = 0; u < 2; ++u)
#pragma unroll
                for (int j = 0; j < 4; ++j) {
                    acc[p * 2 + u][j] = __builtin_amdgcn_mfma_f32_16x16x32_f16(ap[u][0], bfr[j][0], acc[p * 2 + u][j], 0, 0, 0);
                    acc[p * 2 + u][j] = __builtin_amdgcn_mfma_f32_16x16x32_f16(ap[u][1], bfr[j][1], acc[p * 2 + u][j], 0, 0, 0);
                }
            __builtin_amdgcn_s_setprio(0);
            if (p == 3)
                asm volatile("s_waitcnt vmcnt(0)" ::: "memory");
            __builtin_amdgcn_s_barrier();
        }
    }

    // C/D layout (verified): row = quad*4 + reg, col = lane&15
#pragma unroll
    for (int i = 0; i < 8; ++i)
#pragma unroll
        for (int j = 0; j < 4; ++j) {
            const int row = row0 + wm * 128 + i * 16 + quad * 4;
            const int col = col0 + wn * 64 + j * 16 + fr;
#pragma unroll
            for (int r = 0; r < 4; ++r)
                C[(size_t)(row + r) * N + col] = (f16)acc[i][j][r];
        }
}

// ---------------------------------------------------------------------------
// Elementwise split fp32 -> f16 (hi, lo*2^12). n % 1024 == 0.
// ---------------------------------------------------------------------------
__global__ __launch_bounds__(256)
void split_f32(const float* __restrict__ in, f16* __restrict__ h,
               f16* __restrict__ l, int n)
{
    const int i = (blockIdx.x * 256 + threadIdx.x) * 4;
    if (i >= n) return;
    const float4 v = *(const float4*)(in + i);
    f16 hh[4], ll[4];
    split2(v.x, hh[0], ll[0]);
    split2(v.y, hh[1], ll[1]);
    split2(v.z, hh[2], ll[2]);
    split2(v.w, hh[3], ll[3]);
    *(ushort4*)(h + i) = *(const ushort4*)hh;
    *(ushort4*)(l + i) = *(const ushort4*)ll;
}

// ---------------------------------------------------------------------------
// Transpose + split: in (R,C) fp32 -> out (C,R) f16 hi/lo pairs.
// ---------------------------------------------------------------------------
__global__ __launch_bounds__(256)
void transpose_split(const float* __restrict__ in, f16* __restrict__ oh,
                     f16* __restrict__ ol, int R, int C)
{
    __shared__ float tile[32][33];
    const int tx = threadIdx.x & 31, ty = threadIdx.x >> 5;
    const int ic = blockIdx.x * 32 + tx;
    const int ir = blockIdx.y * 32 + ty;
#pragma unroll
    for (int k = 0; k < 32; k += 8)
        tile[ty + k][tx] = in[(size_t)(ir + k) * C + ic];
    __syncthreads();
    const int oc  = blockIdx.y * 32 + tx;
    const int orr = blockIdx.x * 32 + ty;
#pragma unroll
    for (int k = 0; k < 32; k += 8) {
        f16 h, l;
        split2(tile[tx][ty + k], h, l);
        oh[(size_t)(orr + k) * R + oc] = h;
        ol[(size_t)(orr + k) * R + oc] = l;
    }
}

// ---------------------------------------------------------------------------
// Fused refine + online softmax + PV.
// R14 = R12 body VERBATIM (candidate loop untouched -> VGPR ~40, bitwise-
// identical numerics) + work-stealing ONLY: block pulls rows from
// ctr[bid&7], walking the same contiguous 1024-row chunk as R12's static
// map (bid%8 ~ XCD under round-robin dispatch -> L2 locality preserved,
// now load-balanced within each chunk). R13's regression was the 2-deep
// pipeline's VGPR 40->84 (occupancy 46->31%), not stealing -- this is the
// clean A/B of the straggler hypothesis.
// RACE NOTE: Y (old y, read by ALL blocks) must NOT alias Yout.
// Threshold m-18 (verified). Numerics bitwise-identical to R12 (0.046875).
// ---------------------------------------------------------------------------
#define CAP 1024

__global__ __launch_bounds__(256)
void refine_pv(const f16* __restrict__ S, const float* __restrict__ Kt,
               const float* __restrict__ Y, const float* __restrict__ X,
               float* __restrict__ Yout, f16* __restrict__ Yh,
               int* __restrict__ ctr)
{
    const int chunk = blockIdx.x & 7;
    const int t = threadIdx.x;
    const int wave = t >> 6, lane = t & 63;

    __shared__ float red[4];
    __shared__ float wmax[4], wsum[4];
    __shared__ int cnt;
    __shared__ int rowS;
    __shared__ int idxs[CAP];
    __shared__ float accL[4][1024];    // per-wave rescaled acc (16 KB)

    for (;;) {
        if (t == 0) rowS = atomicAdd(&ctr[chunk], 1);
        __syncthreads();
        const int rs = rowS;            // uniform
        if (rs >= 1024) break;
        const int r = (chunk << 10) | rs;
        const int b = r >> 11;

        // --- 0. krow fragment into registers (per wave; L1-shared) ---
        const float* krow = Kt + (size_t)r * 1024;
        float4 kf[4];
#pragma unroll
        for (int d = 0; d < 4; ++d)
            kf[d] = *(const float4*)(krow + d * 256 + lane * 4);

        // --- 1. approx scores + rowmax ---
        float s[8];
        {
            const v8h sv = *(const v8h*)(S + (size_t)r * 2048 + t * 8);
#pragma unroll
            for (int k = 0; k < 8; ++k) s[k] = (float)sv[k];
        }
        float m = s[0];
#pragma unroll
        for (int k = 1; k < 8; ++k) m = fmaxf(m, s[k]);
#pragma unroll
        for (int off = 32; off > 0; off >>= 1) m = fmaxf(m, __shfl_xor(m, off));
        if (lane == 0) red[wave] = m;
        if (t == 0) cnt = 0;
        __syncthreads();
        m = fmaxf(fmaxf(red[0], red[1]), fmaxf(red[2], red[3]));

        // --- 2. candidate collection ---
        const float thresh = m - 18.0f;
#pragma unroll
        for (int k = 0; k < 8; ++k)
            if (s[k] > thresh) {
                const int p = atomicAdd(&cnt, 1);
                if (p < CAP) idxs[p] = t * 8 + k;
            }
        __syncthreads();
        const int count = min(cnt, CAP);

        // --- 3. fused exact-dot + online softmax + weighted PV (per wave) ---
        const float* ybase = Y + ((size_t)b << 21);
        const float* xbase = X + ((size_t)b << 21);
        float m_run = m;               // approx max ~= exact max (err ~0.05)
        float sum = 0.f;
        float4 acc[4];
#pragma unroll
        for (int d = 0; d < 4; ++d) acc[d] = {0.f, 0.f, 0.f, 0.f};

        for (int j = wave; j < count; j += 4) {
            const int idx = idxs[j];
            const float* yrow = ybase + (size_t)idx * 1024;
            float e = 0.f;
#pragma unroll
            for (int d = 0; d < 4; ++d) {
                const float4 yv = *(const float4*)(yrow + d * 256 + lane * 4);
                e += kf[d].x * yv.x + kf[d].y * yv.y + kf[d].z * yv.z + kf[d].w * yv.w;
            }
#pragma unroll
            for (int off = 32; off > 0; off >>= 1) e += __shfl_xor(e, off);
            if (e > m_run) {           // wave-uniform branch
                const float sc = expf(m_run - e);
                sum *= sc;
#pragma unroll
                for (int d = 0; d < 4; ++d) {
                    acc[d].x *= sc; acc[d].y *= sc; acc[d].z *= sc; acc[d].w *= sc;
                }
                m_run = e;
            }
            const float w = expf(e - m_run);
            sum += w;
            const float* xrow = xbase + (size_t)idx * 1024;
#pragma unroll
            for (int d = 0; d < 4; ++d) {
                const float4 xv = *(const float4*)(xrow + d * 256 + lane * 4);
                acc[d].x += w * xv.x; acc[d].y += w * xv.y;
                acc[d].z += w * xv.z; acc[d].w += w * xv.w;
            }
        }

        // --- 4. cross-wave merge ---
        if (lane == 0) { wmax[wave] = m_run; wsum[wave] = sum; }
        __syncthreads();
        const float M = fmaxf(fmaxf(wmax[0], wmax[1]), fmaxf(wmax[2], wmax[3]));
        float Stot = 0.f;
#pragma unroll
        for (int v = 0; v < 4; ++v) Stot += wsum[v] * expf(wmax[v] - M);
        const float scale = expf(m_run - M) / Stot;
#pragma unroll
        for (int d = 0; d < 4; ++d) {
            const int e0 = d * 256 + lane * 4;
            float4 a = acc[d];
            a.x *= scale; a.y *= scale; a.z *= scale; a.w *= scale;
            *(float4*)&accL[wave][e0] = a;
        }
        __syncthreads();

        // --- 5. 4-way sum + write (thread t owns elems t*4..t*4+3) ---
        const int e0 = t * 4;
        float4 o = *(const float4*)&accL[0][e0];
        const float4 o1 = *(const float4*)&accL[1][e0];
        const float4 o2 = *(const float4*)&accL[2][e0];
        const float4 o3 = *(const float4*)&accL[3][e0];
        o.x += o1.x + o2.x + o3.x;
        o.y += o1.y + o2.y + o3.y;
        o.z += o1.z + o2.z + o3.z;
        o.w += o1.w + o2.w + o3.w;

        const size_t oo = (size_t)r * 1024 + e0;
        *(float4*)(Yout + oo) = o;
        f16 h[4] = {(f16)o.x, (f16)o.y, (f16)o.z, (f16)o.w};
        *(ushort4*)(Yh + oo) = *(const ushort4*)h;

        __syncthreads();   // accL/idxs reuse across stolen rows
    }
}

// ---------------------------------------------------------------------------
// Orchestration.  B=4, N=2048, D=1024, n_iters=5.
//   W~ = Wk^T @ Wq (tiny 2-limb);  K~ = x @ W~ (256x128 phase-split 2-limb).
//   per iter: S~ = K~ @ y^T (256-tile phase-split swizzled f16 GEMM) ->
//   fused refine/online-softmax/PV (work-stealing, XCD-chunked, R12 body).
//   y fp32 ping-pongs; final write -> d_out. Steal counters: 5 iters x 8
//   chunks, zeroed once up front (each iteration uses its own slot).
// ---------------------------------------------------------------------------
extern "C" void kernel_launch(void* const* d_in, const int* in_sizes, int n_in,
                              void* d_out, int out_size, void* d_ws, size_t ws_size,
                              hipStream_t stream)
{
    const float* x  = (const float*)d_in[0];   // (4,2048,1024)
    const float* Wq = (const float*)d_in[1];   // (1024,1024)
    const float* Wk = (const float*)d_in[2];   // (1024,1024)
    const int n_iters = 5;                     // fixed by setup_inputs

    const size_t NXe = 8388608;    // 4*2048*1024
    const size_t NWe = 1048576;    // 1024*1024
    const size_t NSe = 16777216;   // 4*2048*2048

    char* p = (char*)d_ws;
    f16* xh   = (f16*)p; p += NXe * 2;     // x hi limb (= iter-0 y f16)
    f16* xl   = (f16*)p; p += NXe * 2;
    f16* wkth = (f16*)p; p += NWe * 2;     // Wk^T limbs
    f16* wktl = (f16*)p; p += NWe * 2;
    f16* wqth = (f16*)p; p += NWe * 2;     // Wq^T limbs
    f16* wqtl = (f16*)p; p += NWe * 2;
    f16* vth  = (f16*)p; p += NWe * 2;     // Vt = (Wk^T Wq)^T limbs
    f16* vtl  = (f16*)p; p += NWe * 2;
    float* kt32 = (float*)p; p += NXe * 4; // K~ fp32 (exact refinement)
    f16*  kt16  = (f16*)p;  p += NXe * 2;  // K~ f16 (approx GEMM)
    f16*  st    = (f16*)p;  p += NSe * 2;  // approx scores f16
    f16*  yh    = (f16*)p;  p += NXe * 2;  // y f16 (next iter)
    float* y1   = (float*)p; p += NXe * 4; // y fp32 ping
    float* y2   = (float*)p; p += NXe * 4; // y fp32 pong
    int* ctr    = (int*)p;   p += 256;     // 5 iters x 8 chunk counters
    if ((size_t)(p - (char*)d_ws) > ws_size) return;  // fail loudly

    float* out = (float*)d_out;

    // --- precompute ---
    hipMemsetAsync(ctr, 0, 5 * 8 * sizeof(int), stream);
    split_f32<<<dim3(NXe / 1024), dim3(256), 0, stream>>>(x, xh, xl, (int)NXe);
    transpose_split<<<dim3(32, 32), dim3(256), 0, stream>>>(Wk, wkth, wktl, 1024, 1024);
    transpose_split<<<dim3(32, 32), dim3(256), 0, stream>>>(Wq, wqth, wqtl, 1024, 1024);
    // Vt[j,i] = sum_d Wq[d,j] Wk[d,i]  (= (Wk^T Wq)^T), 2-limb out
    gemm_nt_2limb<<<dim3(8, 8), dim3(256), 0, stream>>>(
        wqth, wqtl, wkth, wktl, nullptr, vth, vtl, 1, 1024, 1024);
    // K~[m,j] = sum_d x[m,d] Vt[j,d]  (M=8192), fp32 + f16 hi out
    gemm_nt_2limb_256<<<dim3(256), dim3(512), 0, stream>>>(
        xh, xl, vth, vtl, kt32, kt16, 1024, 1024);

    // --- iterations (y double-buffered; final write -> d_out) ---
    const float* yr = x;               // y to READ this iteration (old y)
    float* pingpong[2] = {y1, y2};
    for (int it = 0; it < n_iters; ++it) {
        float* yw = (it == n_iters - 1) ? out : pingpong[it & 1];
        const f16* Bop = (it == 0) ? xh : yh;
        // S~_b = K~_b @ y_b^T  (M=2048, N=2048, K=1024, batch 4), f16 out
        gemm_nt_f16_256<<<dim3(8, 8, 4), dim3(512), 0, stream>>>(
            kt16, Bop, st, 2048, 1024,
            (size_t)2048 * 1024, (size_t)2048 * 1024, (size_t)2048 * 2048);
        // fused candidate refine + online softmax + PV (reads yr, writes yw)
        refine_pv<<<dim3(2048), dim3(256), 0, stream>>>(
            st, kt32, yr, x, yw, yh, ctr + it * 8);
        yr = yw;
    }
}

// Round 15
// 682.440 us; speedup vs baseline: 1.5304x; 1.5304x over previous
//
#include <hip/hip_runtime.h>
#include <cstdint>

typedef _Float16 f16;
typedef __attribute__((ext_vector_type(8))) _Float16 v8h;
typedef __attribute__((ext_vector_type(4))) float v4f;

#define LO_SCALE 4096.0f           // 2^12
#define LO_INV   2.44140625e-4f    // 2^-12

// fp32 -> (hi, lo*2^12) fp16 pair. hi + lo*2^-12 represents f to ~2^-23 rel.
__device__ __forceinline__ void split2(float f, f16& h, f16& l) {
    h = (f16)f;
    l = (f16)((f - (float)h) * LO_SCALE);
}

// global -> LDS async copy, 16B per lane (wave-uniform LDS base + lane*16).
__device__ __forceinline__ void gload_lds16(const void* g, void* l) {
    __builtin_amdgcn_global_load_lds(
        (const __attribute__((address_space(1))) unsigned int*)(uintptr_t)g,
        (__attribute__((address_space(3))) unsigned int*)(unsigned int)(uintptr_t)l,
        16, 0, 0);
}

// ---------------------------------------------------------------------------
// 2-limb fp16 NT GEMM (128^2, 2-barrier). Kept ONLY for the tiny Vt GEMM.
// ---------------------------------------------------------------------------
__global__ __launch_bounds__(256)
void gemm_nt_2limb(const f16* __restrict__ A1, const f16* __restrict__ A2,
                   const f16* __restrict__ B1, const f16* __restrict__ B2,
                   float* __restrict__ C32, f16* __restrict__ Ch,
                   f16* __restrict__ Cl, int mode, int N, int K)
{
    __shared__ f16 lds[4 * 128 * 32];   // 32 KB: A1,A2,B1,B2 tiles
    f16* lA1 = lds;
    f16* lA2 = lds + 128 * 32;
    f16* lB1 = lds + 2 * 128 * 32;
    f16* lB2 = lds + 3 * 128 * 32;

    const int tid  = threadIdx.x;
    const int lane = tid & 63;
    const int wave = tid >> 6;
    const int wm = wave >> 1, wn = wave & 1;
    const int fr = lane & 15, quad = lane >> 4;
    const int row0 = blockIdx.y * 128;
    const int col0 = blockIdx.x * 128;
    const int l4 = lane >> 2;
    const int c8 = (lane & 3) * 8;

    v4f accB[4][4], accS[4][4];
#pragma unroll
    for (int i = 0; i < 4; ++i)
#pragma unroll
        for (int j = 0; j < 4; ++j) {
            accB[i][j] = {0.f, 0.f, 0.f, 0.f};
            accS[i][j] = {0.f, 0.f, 0.f, 0.f};
        }

    for (int k0 = 0; k0 < K; k0 += 32) {
#pragma unroll
        for (int t = 0; t < 2; ++t) {
            const int slot = wave + 4 * t;
            const int r = slot * 16 + l4;
            const size_t ga = (size_t)(row0 + r) * K + (k0 + c8);
            const size_t gb = (size_t)(col0 + r) * K + (k0 + c8);
            const unsigned loff = slot * 1024;
            gload_lds16(A1 + ga, (char*)lA1 + loff);
            gload_lds16(A2 + ga, (char*)lA2 + loff);
            gload_lds16(B1 + gb, (char*)lB1 + loff);
            gload_lds16(B2 + gb, (char*)lB2 + loff);
        }
        __syncthreads();

        v8h a1[4], a2[4], b1[4], b2[4];
#pragma unroll
        for (int i = 0; i < 4; ++i) {
            const int off = (wm * 64 + i * 16 + fr) * 32 + quad * 8;
            a1[i] = *(const v8h*)&lA1[off];
            a2[i] = *(const v8h*)&lA2[off];
        }
#pragma unroll
        for (int j = 0; j < 4; ++j) {
            const int off = (wn * 64 + j * 16 + fr) * 32 + quad * 8;
            b1[j] = *(const v8h*)&lB1[off];
            b2[j] = *(const v8h*)&lB2[off];
        }
#pragma unroll
        for (int i = 0; i < 4; ++i)
#pragma unroll
            for (int j = 0; j < 4; ++j) {
                accB[i][j] = __builtin_amdgcn_mfma_f32_16x16x32_f16(a1[i], b1[j], accB[i][j], 0, 0, 0);
                accS[i][j] = __builtin_amdgcn_mfma_f32_16x16x32_f16(a2[i], b1[j], accS[i][j], 0, 0, 0);
                accS[i][j] = __builtin_amdgcn_mfma_f32_16x16x32_f16(a1[i], b2[j], accS[i][j], 0, 0, 0);
            }
        __syncthreads();
    }

    // C/D layout (verified): row = quad*4 + reg, col = lane&15
#pragma unroll
    for (int i = 0; i < 4; ++i)
#pragma unroll
        for (int j = 0; j < 4; ++j) {
            const int row = row0 + wm * 64 + i * 16 + quad * 4;
            const int col = col0 + wn * 64 + j * 16 + fr;
#pragma unroll
            for (int r = 0; r < 4; ++r) {
                const float v = accB[i][j][r] + accS[i][j][r] * LO_INV;
                const size_t off = (size_t)(row + r) * N + col;
                if (mode == 0) {
                    C32[off] = v;
                } else if (mode == 1) {
                    f16 h, l; split2(v, h, l);
                    Ch[off] = h; Cl[off] = l;
                } else {
                    C32[off] = v;
                    Ch[off] = (f16)v;
                }
            }
        }
}

// ---------------------------------------------------------------------------
// 2-limb fp16 NT GEMM, 256x128 tile, BK=32, 8 waves, phase-split schedule
// + T2 swizzle + XCD-chunked mapping. K~ only (writes C32 fp32 + Ch f16).
// Verified R7.
// ---------------------------------------------------------------------------
__global__ __launch_bounds__(512)
void gemm_nt_2limb_256(const f16* __restrict__ A1, const f16* __restrict__ A2,
                       const f16* __restrict__ B1, const f16* __restrict__ B2,
                       float* __restrict__ C32, f16* __restrict__ Ch,
                       int N, int K)
{
    // [buf(2)][A1 16K | A2 16K | B1 8K | B2 8K] = 96 KB
    __shared__ f16 lds[2 * 24576];

    const int bid = blockIdx.x;
    const int lid = (bid & 7) * 32 + (bid >> 3);   // XCD-chunked, bijective
    const int col0 = (lid & 7) * 128;              // N strip (8)
    const int row0 = (lid >> 3) * 256;             // M strip (32)

    const int tid  = threadIdx.x;
    const int lane = tid & 63;
    const int wave = tid >> 6;          // 0..7
    const int wm = wave >> 1;           // 0..3  (64-row strip)
    const int wn = wave & 1;            // 0..1  (64-col strip)
    const int fr = lane & 15, quad = lane >> 4;
    const int NT = K >> 5;

    const int trow = tid >> 2;          // 0..127
    const int tchunk = tid & 3;

    auto STAGE = [&](int T) {
        const unsigned bufB = (unsigned)(T & 1) * 49152u;   // bytes
        const int k0 = T * 32;
#pragma unroll
        for (int rd = 0; rd < 2; ++rd) {
            const int r = trow + rd * 128;
            const int sc = (tchunk ^ ((r >> 1) & 3)) * 8;   // f16 units
            const size_t ga = (size_t)(row0 + r) * K + k0 + sc;
            const unsigned dof = (unsigned)(rd * 8192 + wave * 1024);
            gload_lds16(A1 + ga, (char*)lds + bufB + dof);
            gload_lds16(A2 + ga, (char*)lds + bufB + 16384u + dof);
        }
        {
            const int r = trow;
            const int sc = (tchunk ^ ((r >> 1) & 3)) * 8;
            const size_t gb = (size_t)(col0 + r) * K + k0 + sc;
            const unsigned dof = (unsigned)(wave * 1024);
            gload_lds16(B1 + gb, (char*)lds + bufB + 32768u + dof);
            gload_lds16(B2 + gb, (char*)lds + bufB + 40960u + dof);
        }
    };

    auto LRD = [&](const f16* base, int row) {
        return *(const v8h*)&base[row * 32 + ((quad ^ ((row >> 1) & 3)) * 8)];
    };

    v4f accB[4][4], accS[4][4];
#pragma unroll
    for (int i = 0; i < 4; ++i)
#pragma unroll
        for (int j = 0; j < 4; ++j) {
            accB[i][j] = {0.f, 0.f, 0.f, 0.f};
            accS[i][j] = {0.f, 0.f, 0.f, 0.f};
        }

    STAGE(0);
    asm volatile("s_waitcnt vmcnt(0)" ::: "memory");
    __builtin_amdgcn_s_barrier();

    for (int t = 0; t < NT; ++t) {
        const int bc = (t & 1) * 24576;             // f16 units
        const f16* lA1 = lds + bc;
        const f16* lA2 = lds + bc + 8192;
        const f16* lB1 = lds + bc + 16384;
        const f16* lB2 = lds + bc + 20480;

        // ---- phase 0: all B frags + A i=0; issue next tile ----
        v8h b1[4], b2[4];
#pragma unroll
        for (int j = 0; j < 4; ++j) {
            b1[j] = LRD(lB1, wn * 64 + j * 16 + fr);
            b2[j] = LRD(lB2, wn * 64 + j * 16 + fr);
        }
        {
            v8h a1 = LRD(lA1, wm * 64 + 0 + fr);
            v8h a2 = LRD(lA2, wm * 64 + 0 + fr);
            if (t + 1 < NT) STAGE(t + 1);
            __builtin_amdgcn_s_barrier();
            asm volatile("s_waitcnt lgkmcnt(0)" ::: "memory");
            __builtin_amdgcn_s_setprio(1);
#pragma unroll
            for (int j = 0; j < 4; ++j) {
                accB[0][j] = __builtin_amdgcn_mfma_f32_16x16x32_f16(a1, b1[j], accB[0][j], 0, 0, 0);
                accS[0][j] = __builtin_amdgcn_mfma_f32_16x16x32_f16(a2, b1[j], accS[0][j], 0, 0, 0);
                accS[0][j] = __builtin_amdgcn_mfma_f32_16x16x32_f16(a1, b2[j], accS[0][j], 0, 0, 0);
            }
            __builtin_amdgcn_s_setprio(0);
            __builtin_amdgcn_s_barrier();
        }

        // ---- phases 1..3: A i=p; phase 3 carries the tile vmcnt ----
#pragma unroll
        for (int p = 1; p < 4; ++p) {
            v8h a1 = LRD(lA1, wm * 64 + p * 16 + fr);
            v8h a2 = LRD(lA2, wm * 64 + p * 16 + fr);
            __builtin_amdgcn_s_barrier();
            asm volatile("s_waitcnt lgkmcnt(0)" ::: "memory");
            __builtin_amdgcn_s_setprio(1);
#pragma unroll
            for (int j = 0; j < 4; ++j) {
                accB[p][j] = __builtin_amdgcn_mfma_f32_16x16x32_f16(a1, b1[j], accB[p][j], 0, 0, 0);
                accS[p][j] = __builtin_amdgcn_mfma_f32_16x16x32_f16(a2, b1[j], accS[p][j], 0, 0, 0);
                accS[p][j] = __builtin_amdgcn_mfma_f32_16x16x32_f16(a1, b2[j], accS[p][j], 0, 0, 0);
            }
            __builtin_amdgcn_s_setprio(0);
            if (p == 3)
                asm volatile("s_waitcnt vmcnt(0)" ::: "memory");
            __builtin_amdgcn_s_barrier();
        }
    }

    // C/D layout (verified): row = quad*4 + reg, col = lane&15; C32 + Ch
#pragma unroll
    for (int i = 0; i < 4; ++i)
#pragma unroll
        for (int j = 0; j < 4; ++j) {
            const int row = row0 + wm * 64 + i * 16 + quad * 4;
            const int col = col0 + wn * 64 + j * 16 + fr;
#pragma unroll
            for (int r = 0; r < 4; ++r) {
                const float v = accB[i][j][r] + accS[i][j][r] * LO_INV;
                const size_t off = (size_t)(row + r) * N + col;
                C32[off] = v;
                Ch[off] = (f16)v;
            }
        }
}

// ---------------------------------------------------------------------------
// Single-limb f16 NT GEMM, 256x256 tile, BK=64, 8 waves, phase-split +
// T2 XOR-swizzle (verified R6). Batched via blockIdx.z.
// ---------------------------------------------------------------------------
__global__ __launch_bounds__(512)
void gemm_nt_f16_256(const f16* __restrict__ A, const f16* __restrict__ B,
                     f16* __restrict__ C, int N, int K,
                     size_t sA, size_t sB, size_t sC)
{
    // [buf(2)][op(2): A,B][256 rows][64 k] f16 = 128 KB
    __shared__ f16 lds[2 * 2 * 256 * 64];

    const int bz = blockIdx.z;
    A += (size_t)bz * sA; B += (size_t)bz * sB; C += (size_t)bz * sC;

    const int tid  = threadIdx.x;
    const int lane = tid & 63;
    const int wave = tid >> 6;          // 0..7
    const int wm = wave >> 2;           // 0..1  (M half)
    const int wn = wave & 3;            // 0..3  (N quarter)
    const int fr = lane & 15, quad = lane >> 4;
    const int row0 = blockIdx.y * 256;
    const int col0 = blockIdx.x * 256;
    const int NT = K >> 6;

    const int rsub = tid >> 3;          // 0..63: row within a 64-row group
    const int csub = (((tid & 7) ^ ((tid >> 3) & 7)) * 8);

    auto STAGE = [&](int T) {
        const unsigned bufB = (unsigned)(T & 1) * 65536u;   // bytes
#pragma unroll
        for (int q = 0; q < 4; ++q) {
            const f16* op = (q >= 2) ? B : A;
            const int r0 = ((q >= 2) ? col0 : row0) + (q & 1) * 128;
#pragma unroll
            for (int t2 = 0; t2 < 2; ++t2) {
                const f16* g = op + (size_t)(r0 + t2 * 64 + rsub) * K + T * 64 + csub;
                gload_lds16(g, (char*)lds + bufB + (unsigned)(q >> 1) * 32768u
                                 + (unsigned)(q & 1) * 16384u
                                 + (unsigned)(t2 * 8192 + wave * 1024));
            }
        }
    };

    auto LRD = [&](const f16* base, int row, int ks) {
        return *(const v8h*)&base[row * 64 + (((ks * 4 + quad) ^ (row & 7)) * 8)];
    };

    v4f acc[8][4];
#pragma unroll
    for (int i = 0; i < 8; ++i)
#pragma unroll
        for (int j = 0; j < 4; ++j)
            acc[i][j] = {0.f, 0.f, 0.f, 0.f};

    STAGE(0);
    asm volatile("s_waitcnt vmcnt(0)" ::: "memory");
    __builtin_amdgcn_s_barrier();

    for (int t = 0; t < NT; ++t) {
        const int bc = (t & 1) * 32768;             // f16 units
        const f16* lA = lds + bc;
        const f16* lB = lds + bc + 16384;

        // ---- phase 0: B-frags (whole tile) + A i=0,1; issue next tile ----
        v8h bfr[4][2];
#pragma unroll
        for (int j = 0; j < 4; ++j)
#pragma unroll
            for (int ks = 0; ks < 2; ++ks)
                bfr[j][ks] = LRD(lB, wn * 64 + j * 16 + fr, ks);
        {
            v8h a0[2], a1[2];
#pragma unroll
            for (int ks = 0; ks < 2; ++ks) {
                a0[ks] = LRD(lA, wm * 128 + 0 + fr, ks);
                a1[ks] = LRD(lA, wm * 128 + 16 + fr, ks);
            }
            if (t + 1 < NT) STAGE(t + 1);
            __builtin_amdgcn_s_barrier();
            asm volatile("s_waitcnt lgkmcnt(0)" ::: "memory");
            __builtin_amdgcn_s_setprio(1);
#pragma unroll
            for (int j = 0; j < 4; ++j) {
                acc[0][j] = __builtin_amdgcn_mfma_f32_16x16x32_f16(a0[0], bfr[j][0], acc[0][j], 0, 0, 0);
                acc[0][j] = __builtin_amdgcn_mfma_f32_16x16x32_f16(a0[1], bfr[j][1], acc[0][j], 0, 0, 0);
                acc[1][j] = __builtin_amdgcn_mfma_f32_16x16x32_f16(a1[0], bfr[j][0], acc[1][j], 0, 0, 0);
                acc[1][j] = __builtin_amdgcn_mfma_f32_16x16x32_f16(a1[1], bfr[j][1], acc[1][j], 0, 0, 0);
            }
            __builtin_amdgcn_s_setprio(0);
            __builtin_amdgcn_s_barrier();
        }

        // ---- phases 1..3: A i=2p..2p+1; phase 3 carries the tile vmcnt ----
#pragma unroll
        for (int p = 1; p < 4; ++p) {
            v8h ap[2][2];
#pragma unroll
            for (int u = 0; u < 2; ++u)
#pragma unroll
                for (int ks = 0; ks < 2; ++ks)
                    ap[u][ks] = LRD(lA, wm * 128 + (p * 2 + u) * 16 + fr, ks);
            __builtin_amdgcn_s_barrier();
            asm volatile("s_waitcnt lgkmcnt(0)" ::: "memory");
            __builtin_amdgcn_s_setprio(1);
#pragma unroll
            for (int u = 0; u < 2; ++u)
#pragma unroll
                for (int j = 0; j < 4; ++j) {
                    acc[p * 2 + u][j] = __builtin_amdgcn_mfma_f32_16x16x32_f16(ap[u][0], bfr[j][0], acc[p * 2 + u][j], 0, 0, 0);
                    acc[p * 2 + u][j] = __builtin_amdgcn_mfma_f32_16x16x32_f16(ap[u][1], bfr[j][1], acc[p * 2 + u][j], 0, 0, 0);
                }
            __builtin_amdgcn_s_setprio(0);
            if (p == 3)
                asm volatile("s_waitcnt vmcnt(0)" ::: "memory");
            __builtin_amdgcn_s_barrier();
        }
    }

    // C/D layout (verified): row = quad*4 + reg, col = lane&15
#pragma unroll
    for (int i = 0; i < 8; ++i)
#pragma unroll
        for (int j = 0; j < 4; ++j) {
            const int row = row0 + wm * 128 + i * 16 + quad * 4;
            const int col = col0 + wn * 64 + j * 16 + fr;
#pragma unroll
            for (int r = 0; r < 4; ++r)
                C[(size_t)(row + r) * N + col] = (f16)acc[i][j][r];
        }
}

// ---------------------------------------------------------------------------
// Elementwise split fp32 -> f16 (hi, lo*2^12). n % 1024 == 0.
// ---------------------------------------------------------------------------
__global__ __launch_bounds__(256)
void split_f32(const float* __restrict__ in, f16* __restrict__ h,
               f16* __restrict__ l, int n)
{
    const int i = (blockIdx.x * 256 + threadIdx.x) * 4;
    if (i >= n) return;
    const float4 v = *(const float4*)(in + i);
    f16 hh[4], ll[4];
    split2(v.x, hh[0], ll[0]);
    split2(v.y, hh[1], ll[1]);
    split2(v.z, hh[2], ll[2]);
    split2(v.w, hh[3], ll[3]);
    *(ushort4*)(h + i) = *(const ushort4*)hh;
    *(ushort4*)(l + i) = *(const ushort4*)ll;
}

// ---------------------------------------------------------------------------
// Transpose + split: in (R,C) fp32 -> out (C,R) f16 hi/lo pairs.
// ---------------------------------------------------------------------------
__global__ __launch_bounds__(256)
void transpose_split(const float* __restrict__ in, f16* __restrict__ oh,
                     f16* __restrict__ ol, int R, int C)
{
    __shared__ float tile[32][33];
    const int tx = threadIdx.x & 31, ty = threadIdx.x >> 5;
    const int ic = blockIdx.x * 32 + tx;
    const int ir = blockIdx.y * 32 + ty;
#pragma unroll
    for (int k = 0; k < 32; k += 8)
        tile[ty + k][tx] = in[(size_t)(ir + k) * C + ic];
    __syncthreads();
    const int oc  = blockIdx.y * 32 + tx;
    const int orr = blockIdx.x * 32 + ty;
#pragma unroll
    for (int k = 0; k < 32; k += 8) {
        f16 h, l;
        split2(tile[tx][ty + k], h, l);
        oh[(size_t)(orr + k) * R + oc] = h;
        ol[(size_t)(orr + k) * R + oc] = l;
    }
}

// ---------------------------------------------------------------------------
// Fused refine + online softmax + PV.
// R15 = R12 VERBATIM (static XCD-chunked map, one row per block -- R13/R14
// proved persistent-block stealing serializes rows and loses to the CP's
// natural cross-block overlap) + ONE change: the X-row load is issued
// TOGETHER with the Y-row load (X depends only on idx, not on the dot), so
// each candidate round pays max(Ylat,Xlat)+dot instead of Ylat+dot+Xlat.
// Costs ~16 VGPR (xv[4] live across the reduce); LDS still the occupancy
// limiter (7 blocks/CU) so occupancy is unchanged. Accumulation math is
// untouched -> bitwise-identical numerics (0.046875).
// RACE NOTE: Y (old y, read by ALL blocks) must NOT alias Yout.
// ---------------------------------------------------------------------------
#define CAP 1024

__global__ __launch_bounds__(256)
void refine_pv(const f16* __restrict__ S, const float* __restrict__ Kt,
               const float* __restrict__ Y, const float* __restrict__ X,
               float* __restrict__ Yout, f16* __restrict__ Yh)
{
    const int bid = blockIdx.x;
    const int r = ((bid & 7) << 10) | (bid >> 3);   // XCD-chunked, bijective
    const int b = r >> 11;
    const int t = threadIdx.x;
    const int wave = t >> 6, lane = t & 63;

    __shared__ float red[4];
    __shared__ float wmax[4], wsum[4];
    __shared__ int cnt;
    __shared__ int idxs[CAP];
    __shared__ float accL[4][1024];    // per-wave rescaled acc (16 KB)

    // --- 0. krow fragment into registers (per wave; L1-shared) ---
    const float* krow = Kt + (size_t)r * 1024;
    float4 kf[4];
#pragma unroll
    for (int d = 0; d < 4; ++d)
        kf[d] = *(const float4*)(krow + d * 256 + lane * 4);

    // --- 1. approx scores + rowmax ---
    float s[8];
    {
        const v8h sv = *(const v8h*)(S + (size_t)r * 2048 + t * 8);
#pragma unroll
        for (int k = 0; k < 8; ++k) s[k] = (float)sv[k];
    }
    float m = s[0];
#pragma unroll
    for (int k = 1; k < 8; ++k) m = fmaxf(m, s[k]);
#pragma unroll
    for (int off = 32; off > 0; off >>= 1) m = fmaxf(m, __shfl_xor(m, off));
    if (lane == 0) red[wave] = m;
    if (t == 0) cnt = 0;
    __syncthreads();
    m = fmaxf(fmaxf(red[0], red[1]), fmaxf(red[2], red[3]));

    // --- 2. candidate collection ---
    const float thresh = m - 18.0f;
#pragma unroll
    for (int k = 0; k < 8; ++k)
        if (s[k] > thresh) {
            const int p = atomicAdd(&cnt, 1);
            if (p < CAP) idxs[p] = t * 8 + k;
        }
    __syncthreads();
    const int count = min(cnt, CAP);

    // --- 3. fused exact-dot + online softmax + weighted PV (per wave) ---
    //     Y and X rows for a candidate are issued TOGETHER (R15 change).
    const float* ybase = Y + ((size_t)b << 21);
    const float* xbase = X + ((size_t)b << 21);
    float m_run = m;                   // approx max ~= exact max (err ~0.05)
    float sum = 0.f;
    float4 acc[4];
#pragma unroll
    for (int d = 0; d < 4; ++d) acc[d] = {0.f, 0.f, 0.f, 0.f};

    for (int j = wave; j < count; j += 4) {
        const int idx = idxs[j];
        const float* yrow = ybase + (size_t)idx * 1024;
        const float* xrow = xbase + (size_t)idx * 1024;
        float4 yv[4], xv[4];
#pragma unroll
        for (int d = 0; d < 4; ++d) {
            yv[d] = *(const float4*)(yrow + d * 256 + lane * 4);
            xv[d] = *(const float4*)(xrow + d * 256 + lane * 4);
        }
        float e = 0.f;
#pragma unroll
        for (int d = 0; d < 4; ++d)
            e += kf[d].x * yv[d].x + kf[d].y * yv[d].y
               + kf[d].z * yv[d].z + kf[d].w * yv[d].w;
#pragma unroll
        for (int off = 32; off > 0; off >>= 1) e += __shfl_xor(e, off);
        if (e > m_run) {               // wave-uniform branch
            const float sc = expf(m_run - e);
            sum *= sc;
#pragma unroll
            for (int d = 0; d < 4; ++d) {
                acc[d].x *= sc; acc[d].y *= sc; acc[d].z *= sc; acc[d].w *= sc;
            }
            m_run = e;
        }
        const float w = expf(e - m_run);
        sum += w;
#pragma unroll
        for (int d = 0; d < 4; ++d) {
            acc[d].x += w * xv[d].x; acc[d].y += w * xv[d].y;
            acc[d].z += w * xv[d].z; acc[d].w += w * xv[d].w;
        }
    }

    // --- 4. cross-wave merge ---
    if (lane == 0) { wmax[wave] = m_run; wsum[wave] = sum; }
    __syncthreads();
    const float M = fmaxf(fmaxf(wmax[0], wmax[1]), fmaxf(wmax[2], wmax[3]));
    float Stot = 0.f;
#pragma unroll
    for (int v = 0; v < 4; ++v) Stot += wsum[v] * expf(wmax[v] - M);
    const float scale = expf(m_run - M) / Stot;
#pragma unroll
    for (int d = 0; d < 4; ++d) {
        const int e0 = d * 256 + lane * 4;
        float4 a = acc[d];
        a.x *= scale; a.y *= scale; a.z *= scale; a.w *= scale;
        *(float4*)&accL[wave][e0] = a;
    }
    __syncthreads();

    // --- 5. 4-way sum + write (thread t owns elems t*4..t*4+3) ---
    const int e0 = t * 4;
    float4 o = *(const float4*)&accL[0][e0];
    const float4 o1 = *(const float4*)&accL[1][e0];
    const float4 o2 = *(const float4*)&accL[2][e0];
    const float4 o3 = *(const float4*)&accL[3][e0];
    o.x += o1.x + o2.x + o3.x;
    o.y += o1.y + o2.y + o3.y;
    o.z += o1.z + o2.z + o3.z;
    o.w += o1.w + o2.w + o3.w;

    const size_t oo = (size_t)r * 1024 + e0;
    *(float4*)(Yout + oo) = o;
    f16 h[4] = {(f16)o.x, (f16)o.y, (f16)o.z, (f16)o.w};
    *(ushort4*)(Yh + oo) = *(const ushort4*)h;
}

// ---------------------------------------------------------------------------
// Orchestration.  B=4, N=2048, D=1024, n_iters=5.
//   W~ = Wk^T @ Wq (tiny 2-limb);  K~ = x @ W~ (256x128 phase-split 2-limb).
//   per iter: S~ = K~ @ y^T (256-tile phase-split swizzled f16 GEMM) ->
//   fused refine/online-softmax/PV (XCD-chunked static map). y fp32
//   ping-pongs; final write -> d_out.
// ---------------------------------------------------------------------------
extern "C" void kernel_launch(void* const* d_in, const int* in_sizes, int n_in,
                              void* d_out, int out_size, void* d_ws, size_t ws_size,
                              hipStream_t stream)
{
    const float* x  = (const float*)d_in[0];   // (4,2048,1024)
    const float* Wq = (const float*)d_in[1];   // (1024,1024)
    const float* Wk = (const float*)d_in[2];   // (1024,1024)
    const int n_iters = 5;                     // fixed by setup_inputs

    const size_t NXe = 8388608;    // 4*2048*1024
    const size_t NWe = 1048576;    // 1024*1024
    const size_t NSe = 16777216;   // 4*2048*2048
    const size_t NR  = 8192;       // score rows

    char* p = (char*)d_ws;
    f16* xh   = (f16*)p; p += NXe * 2;     // x hi limb (= iter-0 y f16)
    f16* xl   = (f16*)p; p += NXe * 2;
    f16* wkth = (f16*)p; p += NWe * 2;     // Wk^T limbs
    f16* wktl = (f16*)p; p += NWe * 2;
    f16* wqth = (f16*)p; p += NWe * 2;     // Wq^T limbs
    f16* wqtl = (f16*)p; p += NWe * 2;
    f16* vth  = (f16*)p; p += NWe * 2;     // Vt = (Wk^T Wq)^T limbs
    f16* vtl  = (f16*)p; p += NWe * 2;
    float* kt32 = (float*)p; p += NXe * 4; // K~ fp32 (exact refinement)
    f16*  kt16  = (f16*)p;  p += NXe * 2;  // K~ f16 (approx GEMM)
    f16*  st    = (f16*)p;  p += NSe * 2;  // approx scores f16
    f16*  yh    = (f16*)p;  p += NXe * 2;  // y f16 (next iter)
    float* y1   = (float*)p; p += NXe * 4; // y fp32 ping
    float* y2   = (float*)p; p += NXe * 4; // y fp32 pong
    if ((size_t)(p - (char*)d_ws) > ws_size) return;  // fail loudly

    float* out = (float*)d_out;

    // --- precompute ---
    split_f32<<<dim3(NXe / 1024), dim3(256), 0, stream>>>(x, xh, xl, (int)NXe);
    transpose_split<<<dim3(32, 32), dim3(256), 0, stream>>>(Wk, wkth, wktl, 1024, 1024);
    transpose_split<<<dim3(32, 32), dim3(256), 0, stream>>>(Wq, wqth, wqtl, 1024, 1024);
    // Vt[j,i] = sum_d Wq[d,j] Wk[d,i]  (= (Wk^T Wq)^T), 2-limb out
    gemm_nt_2limb<<<dim3(8, 8), dim3(256), 0, stream>>>(
        wqth, wqtl, wkth, wktl, nullptr, vth, vtl, 1, 1024, 1024);
    // K~[m,j] = sum_d x[m,d] Vt[j,d]  (M=8192), fp32 + f16 hi out
    gemm_nt_2limb_256<<<dim3(256), dim3(512), 0, stream>>>(
        xh, xl, vth, vtl, kt32, kt16, 1024, 1024);

    // --- iterations (y double-buffered; final write -> d_out) ---
    const float* yr = x;               // y to READ this iteration (old y)
    float* pingpong[2] = {y1, y2};
    for (int it = 0; it < n_iters; ++it) {
        float* yw = (it == n_iters - 1) ? out : pingpong[it & 1];
        const f16* Bop = (it == 0) ? xh : yh;
        // S~_b = K~_b @ y_b^T  (M=2048, N=2048, K=1024, batch 4), f16 out
        gemm_nt_f16_256<<<dim3(8, 8, 4), dim3(512), 0, stream>>>(
            kt16, Bop, st, 2048, 1024,
            (size_t)2048 * 1024, (size_t)2048 * 1024, (size_t)2048 * 2048);
        // fused candidate refine + online softmax + PV (reads yr, writes yw)
        refine_pv<<<dim3((unsigned)NR), dim3(256), 0, stream>>>(
            st, kt32, yr, x, yw, yh);
        yr = yw;
    }
}